// Round 2
// baseline (121.504 us; speedup 1.0000x reference)
//
#include <hip/hip_runtime.h>
#include <hip/hip_bf16.h>

// HybridLoss: focal + contrastive + 0.1*graph_reg.  N=8192, D=128.
// v2 restructure (resubmit; round-1 bench failed at container level, no
// kernel signal): 2 launches, no staging pipeline.
//  - pair blocks are SELF-CONTAINED: screen fragments (dims 0..31) built
//    in-register from f32 features; bound sq32 = s32_i + s32_j - 2*dot32
//    (s32 exact f32 via shfl_xor butterfly; bf16 dot via 1 MFMA/tile).
//    Trigger slow path if wave-min sq32 < 2 (bf16 slack; diag always fires).
//    Slow path: full K=128 gram from features (bf16 on the fly) + exact f32
//    row norms (1 row/lane + shfl distribute) -> same scan_slow as v1.
//  - same-label pairs: closed form 2*n_c*S_c - 2*||sum_c f||^2 from prep's
//    column sums (exact, O(N*D)).
//  - finalize folded into launch 2 via last-block pattern. All cross-block
//    dataflow is device-scope atomics ONLY (no release fences / buffer_wbl2
//    -- that thrashed L2 in a previous session). Ordering: s_waitcnt
//    vmcnt(0) between accumulator atomicAdd and counter atomicAdd.
//  - prep (launch 1) re-inits counter/accumulators every replay (ws is
//    re-poisoned by the harness each iteration).

#define N_PTS 8192
#define DIM 128

typedef __bf16 bf16x8 __attribute__((ext_vector_type(8)));
typedef float f32x4 __attribute__((ext_vector_type(4)));

// workspace layout (bytes)
#define VPART_OFF 0                       // float[128][256] col sums (cls0 | cls1)
#define SPART_OFF (128 * 256 * 4)         // float4[128] : {ssq_all, ssq_cls1, n1, 0}
#define CTRL_OFF  (SPART_OFF + 128 * 16)  // u32 counter @0; double accC@8, accF@16, accG@24

#define NPAIR 2080
#define NFOCAL 32
#define NGRAPH 256
#define TOTAL_BLOCKS (NPAIR + NFOCAL + NGRAPH + 1)

__device__ __forceinline__ bf16x8 pack8(const float4 a, const float4 b) {
    bf16x8 r;
    r[0] = (__bf16)a.x; r[1] = (__bf16)a.y; r[2] = (__bf16)a.z; r[3] = (__bf16)a.w;
    r[4] = (__bf16)b.x; r[5] = (__bf16)b.y; r[6] = (__bf16)b.z; r[7] = (__bf16)b.w;
    return r;
}
__device__ __forceinline__ float ssq8(const float4 a, const float4 b) {
    return a.x * a.x + a.y * a.y + a.z * a.z + a.w * a.w
         + b.x * b.x + b.y * b.y + b.z * b.z + b.w * b.w;
}

// ================= launch 1: column sums + sqn sums + ctrl init ================
__global__ __launch_bounds__(256) void prep_kernel(const float* __restrict__ feat,
                                                   const float* __restrict__ targets,
                                                   float* __restrict__ vpart,
                                                   float* __restrict__ spart,
                                                   unsigned long long* __restrict__ ctrl) {
    const int b = blockIdx.x;
    const int tid = threadIdx.x;
    if (b == 128) {
        if (tid == 0) {
            *reinterpret_cast<unsigned*>(ctrl) = 0u;      // counter
            double* a = reinterpret_cast<double*>(ctrl);
            a[1] = 0.0; a[2] = 0.0; a[3] = 0.0;           // accC, accF, accG
        }
        return;
    }
    __shared__ float fA[512], f1[512];
    __shared__ float sred[4][3];
    const int w = tid >> 6, lane = tid & 63;
    const float2* feat2 = reinterpret_cast<const float2*>(feat);
    float2 accA = {0.f, 0.f}, acc1 = {0.f, 0.f};
    float ssqA = 0.f, ssq1 = 0.f, n1 = 0.f;
    int r = b * 64 + w * 16;
    #pragma unroll 4
    for (int i = 0; i < 16; ++i, ++r) {
        const float2 v = feat2[r * 64 + lane];
        const float tr = targets[r];              // wave-uniform
        accA.x += v.x; accA.y += v.y;
        acc1.x += tr * v.x; acc1.y += tr * v.y;
        const float s2 = v.x * v.x + v.y * v.y;
        ssqA += s2; ssq1 += tr * s2; n1 += tr;    // n1 identical across lanes
    }
    fA[w * 128 + 2 * lane] = accA.x; fA[w * 128 + 2 * lane + 1] = accA.y;
    f1[w * 128 + 2 * lane] = acc1.x; f1[w * 128 + 2 * lane + 1] = acc1.y;
    #pragma unroll
    for (int off = 32; off > 0; off >>= 1) {
        ssqA += __shfl_down(ssqA, off);
        ssq1 += __shfl_down(ssq1, off);
    }
    if (lane == 0) { sred[w][0] = ssqA; sred[w][1] = ssq1; sred[w][2] = n1; }
    __syncthreads();
    if (tid < 128) {
        const int d = tid;
        const float c1 = f1[d] + f1[128 + d] + f1[256 + d] + f1[384 + d];
        const float ca = fA[d] + fA[128 + d] + fA[256 + d] + fA[384 + d];
        vpart[b * 256 + tid] = ca - c1;           // class 0
    } else {
        const int d = tid - 128;
        vpart[b * 256 + tid] = f1[d] + f1[128 + d] + f1[256 + d] + f1[384 + d];
    }
    if (tid == 0) {
        float4 s;
        s.x = sred[0][0] + sred[1][0] + sred[2][0] + sred[3][0];
        s.y = sred[0][1] + sred[1][1] + sred[2][1] + sred[3][1];
        s.z = sred[0][2] + sred[1][2] + sred[2][2] + sred[3][2];
        s.w = 0.f;
        *reinterpret_cast<float4*>(spart + b * 4) = s;
    }
}

// ================= slow-path scan (unchanged from verified v1) =================
template<bool DIAG>
__device__ __forceinline__ float scan_slow(const f32x4 (&acc)[4][4],
                                           const f32x4 (&sqni)[4], const f32x4 (&ti4)[4],
                                           const float (&sqnj)[4], const float (&tj4)[4],
                                           int wm, int wn, int quad, int m15) {
    float lsum = 0.f;
    #pragma unroll
    for (int tm = 0; tm < 4; ++tm) {
        #pragma unroll
        for (int tn = 0; tn < 4; ++tn) {
            const int jl = wn * 64 + tn * 16 + m15;
            #pragma unroll
            for (int e = 0; e < 4; ++e) {
                const float sq = sqni[tm][e] + sqnj[tn] - 2.f * acc[tm][tn][e];
                bool excl = (ti4[tm][e] == tj4[tn]);
                if (DIAG) {
                    const int il = wm * 64 + tm * 16 + quad * 4 + e;
                    excl = excl || (jl <= il);
                }
                if (!excl && sq < 1.f) {
                    const float d = sqrtf(fmaxf(sq, 0.f));
                    const float m = 1.f - d;
                    lsum += 2.f * m * m;
                }
            }
        }
    }
    return lsum;
}

// ================= launch 2: pair + focal + graph + closed-form + finalize =====
__global__ __launch_bounds__(256, 4) void main_kernel(const float* __restrict__ feat,
                                                      const float* __restrict__ preds,
                                                      const float* __restrict__ targets,
                                                      const float* __restrict__ gfeat,
                                                      const float* __restrict__ vpart,
                                                      const float* __restrict__ spart,
                                                      unsigned* __restrict__ counter,
                                                      double* __restrict__ accs,
                                                      float* __restrict__ out) {
    __shared__ __align__(16) float smem[1024];
    const int bx = blockIdx.x;
    const int tid = threadIdx.x;
    const int w = tid >> 6, lane = tid & 63;
    double addv = 0.0;
    int acc_idx = 1;

    if (bx < NPAIR) {
        // ---- pair block: 128x128 tile (bi, bj), bi <= bj ----
        const int u = bx;
        const int vv = 2079 - u;
        int k = (int)((sqrtf(8.f * (float)vv + 1.f) - 1.f) * 0.5f);
        while ((k + 1) * (k + 2) / 2 <= vv) ++k;
        while (k * (k + 1) / 2 > vv) --k;
        const int bi = 63 - k;
        const int bj = 63 - (vv - k * (k + 1) / 2);

        const int quad = lane >> 4, m15 = lane & 15;
        const int wm = w >> 1, wn = w & 1;
        const int ibase = bi * 128 + wm * 64, jbase = bj * 128 + wn * 64;

        // screen fragments: dims 0..31, lane(quad,m15) = row t*16+m15, dims 8q..8q+7
        bf16x8 afs[4], bfs[4];
        float sA[4], sB[4];
        #pragma unroll
        for (int t = 0; t < 4; ++t) {
            const float* pa = feat + (ibase + t * 16 + m15) * DIM + 8 * quad;
            const float4 a0 = *reinterpret_cast<const float4*>(pa);
            const float4 a1 = *reinterpret_cast<const float4*>(pa + 4);
            afs[t] = pack8(a0, a1);
            float s = ssq8(a0, a1);
            s += __shfl_xor(s, 16); s += __shfl_xor(s, 32);   // sum over quads
            sA[t] = s;                                        // s32 of row t*16+m15
            const float* pb = feat + (jbase + t * 16 + m15) * DIM + 8 * quad;
            const float4 b0 = *reinterpret_cast<const float4*>(pb);
            const float4 b1 = *reinterpret_cast<const float4*>(pb + 4);
            bfs[t] = pack8(b0, b1);
            float sb = ssq8(b0, b1);
            sb += __shfl_xor(sb, 16); sb += __shfl_xor(sb, 32);
            sB[t] = sb;
        }
        f32x4 acc[4][4];
        #pragma unroll
        for (int a = 0; a < 4; ++a)
            #pragma unroll
            for (int b = 0; b < 4; ++b) acc[a][b] = (f32x4){0.f, 0.f, 0.f, 0.f};
        #pragma unroll
        for (int tm = 0; tm < 4; ++tm)
            #pragma unroll
            for (int tn = 0; tn < 4; ++tn)
                acc[tm][tn] = __builtin_amdgcn_mfma_f32_16x16x32_bf16(
                    afs[tm], bfs[tn], acc[tm][tn], 0, 0, 0);

        // min over tile of sq32 = sA(row) + sB(col) - 2*dot32  (lower bound on sq128)
        float minv = 1e30f;
        #pragma unroll
        for (int tm = 0; tm < 4; ++tm) {
            #pragma unroll
            for (int e = 0; e < 4; ++e) {
                const float sa = __shfl(sA[tm], quad * 4 + e);  // C row = quad*4+e
                #pragma unroll
                for (int tn = 0; tn < 4; ++tn)
                    minv = fminf(minv, sa + sB[tn] - 2.f * acc[tm][tn][e]);
            }
        }

        float lsum = 0.f;
        if (__any(minv < 2.f)) {
            // exact f32 row norms: one i-row + one j-row per lane, then distribute
            float qi = 0.f, qj = 0.f;
            {
                const float4* ri = reinterpret_cast<const float4*>(feat + (ibase + lane) * DIM);
                const float4* rj = reinterpret_cast<const float4*>(feat + (jbase + lane) * DIM);
                #pragma unroll 8
                for (int c2 = 0; c2 < 32; ++c2) {
                    const float4 x = ri[c2]; qi += x.x * x.x + x.y * x.y + x.z * x.z + x.w * x.w;
                    const float4 y = rj[c2]; qj += y.x * y.x + y.y * y.y + y.z * y.z + y.w * y.w;
                }
            }
            f32x4 sqni[4], ti4[4];
            float sqnj[4], tj4[4];
            #pragma unroll
            for (int tm = 0; tm < 4; ++tm) {
                #pragma unroll
                for (int e = 0; e < 4; ++e) sqni[tm][e] = __shfl(qi, tm * 16 + quad * 4 + e);
                ti4[tm] = *reinterpret_cast<const f32x4*>(targets + ibase + tm * 16 + quad * 4);
            }
            #pragma unroll
            for (int tn = 0; tn < 4; ++tn) {
                sqnj[tn] = __shfl(qj, tn * 16 + m15);
                tj4[tn] = targets[jbase + tn * 16 + m15];
            }
            // finish the gram: dims 32..127 (ks = 1..3), accumulate into screen acc
            for (int ks = 1; ks < 4; ++ks) {
                bf16x8 af2[4], bf2[4];
                #pragma unroll
                for (int t = 0; t < 4; ++t) {
                    const float* pa = feat + (ibase + t * 16 + m15) * DIM + 8 * (quad + 4 * ks);
                    af2[t] = pack8(*reinterpret_cast<const float4*>(pa),
                                   *reinterpret_cast<const float4*>(pa + 4));
                    const float* pb = feat + (jbase + t * 16 + m15) * DIM + 8 * (quad + 4 * ks);
                    bf2[t] = pack8(*reinterpret_cast<const float4*>(pb),
                                   *reinterpret_cast<const float4*>(pb + 4));
                }
                #pragma unroll
                for (int tm = 0; tm < 4; ++tm)
                    #pragma unroll
                    for (int tn = 0; tn < 4; ++tn)
                        acc[tm][tn] = __builtin_amdgcn_mfma_f32_16x16x32_bf16(
                            af2[tm], bf2[tn], acc[tm][tn], 0, 0, 0);
            }
            lsum = (bi == bj)
                ? scan_slow<true >(acc, sqni, ti4, sqnj, tj4, wm, wn, quad, m15)
                : scan_slow<false>(acc, sqni, ti4, sqnj, tj4, wm, wn, quad, m15);
            #pragma unroll
            for (int off = 32; off > 0; off >>= 1) lsum += __shfl_down(lsum, off);
        }
        if (lane == 0) smem[w] = lsum;
        __syncthreads();
        if (tid == 0) {
            addv = (double)(smem[0] + smem[1] + smem[2] + smem[3]);
            acc_idx = 1;
        }
    } else if (bx < NPAIR + NFOCAL) {
        // ---- focal ----
        const int b = bx - NPAIR;
        const int i = b * 256 + tid;
        const float p = preds[i], t = targets[i];
        const float bce = fmaxf(p, 0.f) - p * t + log1pf(expf(-fabsf(p)));
        const float pt = expf(-bce);
        const float om = 1.f - pt;
        float fv = 0.25f * om * om * bce;
        #pragma unroll
        for (int off = 32; off > 0; off >>= 1) fv += __shfl_down(fv, off);
        if (lane == 0) smem[w] = fv;
        __syncthreads();
        if (tid == 0) {
            addv = (double)(smem[0] + smem[1] + smem[2] + smem[3]);
            acc_idx = 2;
        }
    } else if (bx < NPAIR + NFOCAL + NGRAPH) {
        // ---- graph regularizer ----
        const int b = bx - NPAIR - NFOCAL;
        float ga = 0.f;
        #pragma unroll
        for (int it = 0; it < 8; ++it) {
            const int r = b * 4 + w + it * 1024;
            if (r < N_PTS - 1) {
                const float2 a = *reinterpret_cast<const float2*>(gfeat + r * DIM + lane * 2);
                const float2 bb = *reinterpret_cast<const float2*>(gfeat + (r + 1) * DIM + lane * 2);
                const float dx = bb.x - a.x, dy = bb.y - a.y;
                float s = dx * dx + dy * dy;
                #pragma unroll
                for (int off = 32; off > 0; off >>= 1) s += __shfl_down(s, off);
                if (lane == 0) ga += sqrtf(s);
            }
        }
        if (lane == 0) smem[w] = ga;
        __syncthreads();
        if (tid == 0) {
            addv = (double)(smem[0] + smem[1] + smem[2] + smem[3]);
            acc_idx = 3;
        }
    } else {
        // ---- closed-form same-label term: 2*n_c*S_c - 2*||v_c||^2 ----
        float V = 0.f;
        #pragma unroll 8
        for (int b2 = 0; b2 < 128; ++b2) V += vpart[b2 * 256 + tid];
        double vsq = (double)V * (double)V;
        #pragma unroll
        for (int off = 32; off > 0; off >>= 1) vsq += __shfl_down(vsq, off);
        double* dred = reinterpret_cast<double*>(smem);
        if (lane == 0) dred[w] = vsq;    // waves 0,1 = class0 dims; 2,3 = class1
        double st = 0.0, s1 = 0.0, n1 = 0.0;
        if (tid < 128) {
            const float4 s = *reinterpret_cast<const float4*>(spart + tid * 4);
            st = s.x; s1 = s.y; n1 = s.z;
        }
        #pragma unroll
        for (int off = 32; off > 0; off >>= 1) {
            st += __shfl_down(st, off);
            s1 += __shfl_down(s1, off);
            n1 += __shfl_down(n1, off);
        }
        if (lane == 0) { dred[4 + w * 3] = st; dred[5 + w * 3] = s1; dred[6 + w * 3] = n1; }
        __syncthreads();
        if (tid == 0) {
            const double v0sq = dred[0] + dred[1];
            const double v1sq = dred[2] + dred[3];
            const double stot = dred[4] + dred[7];   // waves 0,1 hold tids < 128
            const double s1s  = dred[5] + dred[8];
            const double n1s  = dred[6] + dred[9];
            const double n0s = (double)N_PTS - n1s;
            const double s0s = stot - s1s;
            addv = 2.0 * (n0s * s0s - v0sq) + 2.0 * (n1s * s1s - v1sq);
            acc_idx = 1;
        }
    }

    // ---- common tail: atomic contribution + last-block finalize ----
    if (tid == 0) {
        if (addv != 0.0) {
            atomicAdd(accs + acc_idx, addv);
            // drain the accumulator RMW before the counter bump so any block
            // that observes our count also observes our contribution.
            asm volatile("s_waitcnt vmcnt(0)" ::: "memory");
        }
        const unsigned old = atomicAdd(counter, 1u);
        if (old == TOTAL_BLOCKS - 1) {
            const double c = atomicAdd(accs + 1, 0.0);   // coherent atomic reads
            const double f = atomicAdd(accs + 2, 0.0);
            const double g = atomicAdd(accs + 3, 0.0);
            out[0] = (float)(c / ((double)N_PTS * (double)N_PTS)
                             + f / (double)N_PTS
                             + 0.1 * (g / (double)(N_PTS - 1)));
        }
    }
}

extern "C" void kernel_launch(void* const* d_in, const int* in_sizes, int n_in,
                              void* d_out, int out_size, void* d_ws, size_t ws_size,
                              hipStream_t stream) {
    const float* preds    = (const float*)d_in[0];
    const float* targets  = (const float*)d_in[1];
    const float* features = (const float*)d_in[2];
    const float* gfeat    = (const float*)d_in[3];
    char* ws = (char*)d_ws;
    float* vpart = (float*)(ws + VPART_OFF);
    float* spart = (float*)(ws + SPART_OFF);
    unsigned long long* ctrl = (unsigned long long*)(ws + CTRL_OFF);

    prep_kernel<<<129, 256, 0, stream>>>(features, targets, vpart, spart, ctrl);
    main_kernel<<<TOTAL_BLOCKS, 256, 0, stream>>>(features, preds, targets, gfeat,
                                                  vpart, spart,
                                                  (unsigned*)ctrl, (double*)ctrl,
                                                  (float*)d_out);
}